// Round 3
// baseline (224.850 us; speedup 1.0000x reference)
//
#include <hip/hip_runtime.h>

// Problem constants: B=16, K=8, C=64, L=2048
#define BB 16
#define KK 8
#define CC 64
#define LL 2048

constexpr int CL = CC * LL;              // 131072 elems per batch
constexpr int QUADS_PER_BATCH = CL / 4;  // 32768
// K-split mapping: each wave covers 32 quads; lanes 0-31 handle k=0..3,
// lanes 32-63 handle k=4..7 of the SAME 32 quads. 128 quads per 256-thr block.
constexpr int NBLOCKS = (BB * QUADS_PER_BATCH) / 128;  // 4096

#define SIG_OFF 0.11920292202211755f     // 1 - sigmoid(2) = sigmoid(-2)
#define LOG_EPS -16.11809565095832f      // logf(1e-7)

typedef float f32x4 __attribute__((ext_vector_type(4)));

__device__ __forceinline__ float frcp(float x) { return __builtin_amdgcn_rcpf(x); }

__global__ void init_sldj_kernel(const float* __restrict__ sldj_in,
                                 float* __restrict__ sldj_out) {
    int i = threadIdx.x;
    if (i < BB) sldj_out[i] = sldj_in[i];
}

// __launch_bounds__(256, 4): cap 128 VGPRs. Payload is 15 float4 = 60 VGPRs,
// so the ENTIRE load burst provably fits in registers (R0's 27-float4 burst
// did not: VGPR_Count=64 forced consume-before-issue serialization). 4 waves/
// SIMD floor = 16 waves/CU; with no LDS pressure the real cap is VGPR-only.
__global__ __launch_bounds__(256, 4) void coupling_kernel(
    const float* __restrict__ x,
    const float* __restrict__ a,
    const float* __restrict__ bv,
    const float* __restrict__ pi,
    const float* __restrict__ mu,
    const float* __restrict__ s,
    float* __restrict__ out,
    float* __restrict__ sldj_out) {

    const int tid  = threadIdx.x;
    const int lane = tid & 63;
    const int wid  = tid >> 6;
    const int kh   = lane >> 5;                      // k-half: 0 -> k=0..3, 1 -> k=4..7
    const int q    = blockIdx.x * 128 + wid * 32 + (lane & 31);  // global quad
    const int b    = q >> 15;                        // batch (block is within one batch)
    const int base = q * 4;                          // flat elem index into x/a/b/out
    const int rem4 = base - b * CL;                  // rem*4 within batch

    // ---- Load burst: 15 float4 = 60 payload VGPRs, all independent ----
    // Lower/upper lane halves read different k-streams: each load instr is two
    // contiguous 512B segments -> still fully 64B-line coalesced.
    const f32x4 x4 = *(const f32x4*)(x + base);

    const int kb0 = (b * KK + kh * 4) * CL + rem4;   // first k-stream of this half
    f32x4 pi4[4], mu4[4], s4[4];
#pragma unroll
    for (int j = 0; j < 4; ++j) {
        pi4[j] = *(const f32x4*)(pi + kb0 + j * CL);
        mu4[j] = *(const f32x4*)(mu + kb0 + j * CL);
        s4[j]  = *(const f32x4*)(s  + kb0 + j * CL);
    }
    const f32x4 a4 = *(const f32x4*)(a + base);
    const f32x4 b4 = *(const f32x4*)(bv + base);
    __builtin_amdgcn_sched_barrier(0);

    // ---- Linear-domain mixture partial sums over this half's 4 k's ----
    //   Spi = sum_k e^{pi_k}
    //   Nc  = sum_k e^{pi_k} * sigmoid(z_k)            -> u   = Nc/Spi
    //   N1  = sum_k e^{pi_k} * (1 - sigmoid(z_k))      -> 1-u = N1/Spi
    //   Np  = sum_k e^{pi_k} * e^{-s_k} * sig*(1-sig)  -> pdf = Np/Spi
    float Spi[4] = {0.f, 0.f, 0.f, 0.f};
    float Nc[4]  = {0.f, 0.f, 0.f, 0.f};
    float N1[4]  = {0.f, 0.f, 0.f, 0.f};
    float Np[4]  = {0.f, 0.f, 0.f, 0.f};

#pragma unroll
    for (int j = 0; j < 4; ++j) {
#pragma unroll
        for (int e = 0; e < 4; ++e) {
            const float p      = pi4[j][e];
            const float m      = mu4[j][e];
            const float sk     = s4[j][e];
            const float invstd = __expf(-sk);
            const float z      = (x4[e] - m) * invstd;

            // stable sigmoid via t = e^{-|z|}
            const float t  = __expf(-fabsf(z));
            const float r  = frcp(1.f + t);
            const float tr = t * r;
            const float sig  = (z >= 0.f) ? r  : tr;
            const float osig = (z >= 0.f) ? tr : r;

            const float ek = __expf(p);
            Spi[e] += ek;
            Nc[e]  += ek * sig;
            N1[e]  += ek * osig;
            Np[e]  += ek * invstd * sig * osig;
        }
    }

    // ---- Combine k-halves: lane l and lane l^32 hold partials of same quad ----
#pragma unroll
    for (int e = 0; e < 4; ++e) {
        Spi[e] += __shfl_xor(Spi[e], 32, 64);
        Nc[e]  += __shfl_xor(Nc[e],  32, 64);
        N1[e]  += __shfl_xor(N1[e],  32, 64);
        Np[e]  += __shfl_xor(Np[e],  32, 64);
    }
    // Now BOTH halves hold the full-k sums for quad q (same values in l, l^32).

    float contrib = 0.f;
    f32x4 out4;

#pragma unroll
    for (int e = 0; e < 4; ++e) {
        const float lSpi = __logf(Spi[e]);
        const float lu   = fmaxf(__logf(Nc[e]) - lSpi, LOG_EPS);
        const float lomu = fmaxf(__logf(N1[e]) - lSpi, LOG_EPS);
        const float y        = lu - lomu;     // logit
        const float ldj_term = -lu - lomu;
        const float log_pdf  = __logf(Np[e]) - lSpi;

        // scale = sigmoid(a+2) + sigmoid(-2)
        const float ae = a4[e] + 2.f;
        const float t2 = __expf(-fabsf(ae));
        const float r2 = frcp(1.f + t2);
        const float sc = ((ae >= 0.f) ? r2 : t2 * r2) + SIG_OFF;

        out4[e] = (y + b4[e]) * sc;
        contrib += log_pdf + ldj_term + __logf(sc);
    }

    // Upper half duplicates lower half's quads: store/count only lower half.
    if (kh == 0) {
        *(f32x4*)(out + base) = out4;
    } else {
        contrib = 0.f;
    }

    // ---- block reduction, one atomicAdd per block (block is within batch b) ----
#pragma unroll
    for (int off = 32; off > 0; off >>= 1)
        contrib += __shfl_down(contrib, off, 64);

    __shared__ float wsum[4];
    if (lane == 0) wsum[wid] = contrib;
    __syncthreads();
    if (tid == 0) {
        atomicAdd(&sldj_out[b], wsum[0] + wsum[1] + wsum[2] + wsum[3]);
    }
}

extern "C" void kernel_launch(void* const* d_in, const int* in_sizes, int n_in,
                              void* d_out, int out_size, void* d_ws, size_t ws_size,
                              hipStream_t stream) {
    const float* x    = (const float*)d_in[0];
    const float* a    = (const float*)d_in[1];
    const float* bv   = (const float*)d_in[2];
    const float* pi   = (const float*)d_in[3];
    const float* mu   = (const float*)d_in[4];
    const float* s    = (const float*)d_in[5];
    const float* sldj = (const float*)d_in[6];

    float* out      = (float*)d_out;
    float* sldj_out = out + (size_t)BB * CL;  // outputs concat: out, then sldj

    init_sldj_kernel<<<1, 64, 0, stream>>>(sldj, sldj_out);
    coupling_kernel<<<NBLOCKS, 256, 0, stream>>>(x, a, bv, pi, mu, s, out, sldj_out);
}

// Round 4
// 222.999 us; speedup vs baseline: 1.0083x; 1.0083x over previous
//
#include <hip/hip_runtime.h>
#include <stdint.h>

// Problem constants: B=16, K=8, C=64, L=2048
#define BB 16
#define KK 8
#define CC 64
#define LL 2048

constexpr int CL = CC * LL;              // 131072 elems per batch
constexpr int QUADS_PER_BATCH = CL / 4;  // 32768
// K-split: lanes 0-31 handle k=0..3, lanes 32-63 k=4..7 of the same 32 quads.
// 128 quads per 256-thread block.
constexpr int NBLOCKS = (BB * QUADS_PER_BATCH) / 128;  // 4096

#define SIG_OFF 0.11920292202211755f     // 1 - sigmoid(2) = sigmoid(-2)
#define LOG_EPS -16.11809565095832f      // logf(1e-7)

typedef float f32x4 __attribute__((ext_vector_type(4)));

__device__ __forceinline__ float frcp(float x) { return __builtin_amdgcn_rcpf(x); }

// Inline-asm global load: opaque to IR sinking, MachineSink, the pre-RA
// scheduler's pressure heuristics, and SIInsertWaitcnts. Fifteen of these in
// a row GUARANTEES fifteen dwordx4 in flight at ISA level — the thing rounds
// 0-3 tried and the compiler defeated every time (VGPR_Count 64/68/68/32).
// Ordering/consumption is hand-managed with counted vmcnt below.
__device__ __forceinline__ f32x4 gload16(const float* p) {
    f32x4 r;
    asm volatile("global_load_dwordx4 %0, %1, off"
                 : "=v"(r)
                 : "v"((uint64_t)(uintptr_t)p));
    return r;
}

__global__ void init_sldj_kernel(const float* __restrict__ sldj_in,
                                 float* __restrict__ sldj_out) {
    int i = threadIdx.x;
    if (i < BB) sldj_out[i] = sldj_in[i];
}

// __launch_bounds__(256,2): VGPR cap 256 — payload (~64) + accums (16) + temps
// lands ~100-130; a 128 cap risks spill which would void the experiment.
__global__ __launch_bounds__(256, 2) void coupling_kernel(
    const float* __restrict__ x,
    const float* __restrict__ a,
    const float* __restrict__ bv,
    const float* __restrict__ pi,
    const float* __restrict__ mu,
    const float* __restrict__ s,
    float* __restrict__ out,
    float* __restrict__ sldj_out) {

    const int tid  = threadIdx.x;
    const int lane = tid & 63;
    const int wid  = tid >> 6;
    const int kh   = lane >> 5;                       // k-half
    const int q    = blockIdx.x * 128 + wid * 32 + (lane & 31);
    const int b    = q >> 15;                         // batch
    const int base = q * 4;
    const int rem4 = base - b * CL;
    const int kb0  = (b * KK + kh * 4) * CL + rem4;   // first k-stream this half

    // ---- ISA-guaranteed burst: 15 x global_load_dwordx4, issue order fixed ----
    // vm op #:      1    2..13 (p,m,s per j)          14   15
    f32x4 x4 = gload16(x + base);
    f32x4 p4[4], m4[4], s4[4];
#pragma unroll
    for (int j = 0; j < 4; ++j) {
        p4[j] = gload16(pi + kb0 + j * CL);
        m4[j] = gload16(mu + kb0 + j * CL);
        s4[j] = gload16(s  + kb0 + j * CL);
    }
    f32x4 a4 = gload16(a + base);
    f32x4 b4 = gload16(bv + base);

    // ---- Linear-domain mixture partial sums over this half's 4 k's ----
    //   Spi = sum_k e^{pi_k}
    //   Nc  = sum_k e^{pi_k} * sigmoid(z_k)            -> u   = Nc/Spi
    //   N1  = sum_k e^{pi_k} * (1 - sigmoid(z_k))      -> 1-u = N1/Spi
    //   Np  = sum_k e^{pi_k} * e^{-s_k} * sig*(1-sig)  -> pdf = Np/Spi
    float Spi[4] = {0.f, 0.f, 0.f, 0.f};
    float Nc[4]  = {0.f, 0.f, 0.f, 0.f};
    float N1[4]  = {0.f, 0.f, 0.f, 0.f};
    float Np[4]  = {0.f, 0.f, 0.f, 0.f};

#pragma unroll
    for (int j = 0; j < 4; ++j) {
        // Counted wait: stage j's operands (vm ops #1..#(4+3j)) complete,
        // all younger loads remain in flight. Never vmcnt(0) until a/b drain.
        if (j == 0) {
            asm volatile("s_waitcnt vmcnt(11)" ::: "memory");
            asm volatile("" : "+v"(x4));             // tie: x4 valid after wait
        } else if (j == 1) {
            asm volatile("s_waitcnt vmcnt(8)" ::: "memory");
        } else if (j == 2) {
            asm volatile("s_waitcnt vmcnt(5)" ::: "memory");
        } else {
            asm volatile("s_waitcnt vmcnt(2)" ::: "memory");
        }
        // Value-tie through the wait: compute below consumes THESE outputs,
        // so it cannot be scheduled between the load and the wait.
        asm volatile("" : "+v"(p4[j]), "+v"(m4[j]), "+v"(s4[j]));
        __builtin_amdgcn_sched_barrier(0);

#pragma unroll
        for (int e = 0; e < 4; ++e) {
            const float p      = p4[j][e];
            const float m      = m4[j][e];
            const float sk     = s4[j][e];
            const float invstd = __expf(-sk);
            const float z      = (x4[e] - m) * invstd;

            // stable sigmoid via t = e^{-|z|}
            const float t  = __expf(-fabsf(z));
            const float r  = frcp(1.f + t);
            const float tr = t * r;
            const float sig  = (z >= 0.f) ? r  : tr;
            const float osig = (z >= 0.f) ? tr : r;

            const float ek = __expf(p);
            Spi[e] += ek;
            Nc[e]  += ek * sig;
            N1[e]  += ek * osig;
            Np[e]  += ek * invstd * sig * osig;
        }
    }

    // ---- Combine k-halves: lane l and l^32 hold partials of the same quad ----
#pragma unroll
    for (int e = 0; e < 4; ++e) {
        Spi[e] += __shfl_xor(Spi[e], 32, 64);
        Nc[e]  += __shfl_xor(Nc[e],  32, 64);
        N1[e]  += __shfl_xor(N1[e],  32, 64);
        Np[e]  += __shfl_xor(Np[e],  32, 64);
    }

    // Drain a/b (vm ops #14,#15).
    asm volatile("s_waitcnt vmcnt(0)" ::: "memory");
    asm volatile("" : "+v"(a4), "+v"(b4));
    __builtin_amdgcn_sched_barrier(0);

    float contrib = 0.f;
    f32x4 out4;

#pragma unroll
    for (int e = 0; e < 4; ++e) {
        const float lSpi = __logf(Spi[e]);
        const float lu   = fmaxf(__logf(Nc[e]) - lSpi, LOG_EPS);
        const float lomu = fmaxf(__logf(N1[e]) - lSpi, LOG_EPS);
        const float y        = lu - lomu;     // logit
        const float ldj_term = -lu - lomu;
        const float log_pdf  = __logf(Np[e]) - lSpi;

        // scale = sigmoid(a+2) + sigmoid(-2)
        const float ae = a4[e] + 2.f;
        const float t2 = __expf(-fabsf(ae));
        const float r2 = frcp(1.f + t2);
        const float sc = ((ae >= 0.f) ? r2 : t2 * r2) + SIG_OFF;

        out4[e] = (y + b4[e]) * sc;
        contrib += log_pdf + ldj_term + __logf(sc);
    }

    // Upper half duplicates lower half's quads: store/count only lower half.
    if (kh == 0) {
        *(f32x4*)(out + base) = out4;
    } else {
        contrib = 0.f;
    }

    // ---- block reduction, one atomicAdd per block (block is within batch b) ----
#pragma unroll
    for (int off = 32; off > 0; off >>= 1)
        contrib += __shfl_down(contrib, off, 64);

    __shared__ float wsum[4];
    if (lane == 0) wsum[wid] = contrib;
    __syncthreads();
    if (tid == 0) {
        atomicAdd(&sldj_out[b], wsum[0] + wsum[1] + wsum[2] + wsum[3]);
    }
}

extern "C" void kernel_launch(void* const* d_in, const int* in_sizes, int n_in,
                              void* d_out, int out_size, void* d_ws, size_t ws_size,
                              hipStream_t stream) {
    const float* x    = (const float*)d_in[0];
    const float* a    = (const float*)d_in[1];
    const float* bv   = (const float*)d_in[2];
    const float* pi   = (const float*)d_in[3];
    const float* mu   = (const float*)d_in[4];
    const float* s    = (const float*)d_in[5];
    const float* sldj = (const float*)d_in[6];

    float* out      = (float*)d_out;
    float* sldj_out = out + (size_t)BB * CL;  // outputs concat: out, then sldj

    init_sldj_kernel<<<1, 64, 0, stream>>>(sldj, sldj_out);
    coupling_kernel<<<NBLOCKS, 256, 0, stream>>>(x, a, bv, pi, mu, s, out, sldj_out);
}